// Round 7
// baseline (332.803 us; speedup 1.0000x reference)
//
#include <hip/hip_runtime.h>
#include <stdint.h>

// ============================================================================
// ExpertMLP: out = relu(x @ W_fc^T)^2 @ W_proj^T    (fp32 in/out, bf16 MFMA)
// R7: staged-bytes reduction via bigger tiles (empirical law: dur = staged
//     global->LDS bytes / ~17 B/cyc/CU, invariant across R2-R6 structures).
//     GEMM1: 256x256 tile (2 MB/CU staged, was 4). GEMM2: 256x128 (3 MB/CU).
//     512-thread blocks, m97 global_load_lds staging, BK=64, 2 barriers/iter.
// ws: h[64Mi] | x_bf[16Mi] | wfc_bf[8Mi] | wproj_bf[8Mi] = 96 MiB.
// ============================================================================

#define BK 64

typedef __attribute__((ext_vector_type(8))) short bf16x8;   // 8 bf16 = 4 VGPRs
typedef __attribute__((ext_vector_type(4))) float f32x4;    // MFMA C/D

typedef const __attribute__((address_space(1))) unsigned int* gas_u32p;
typedef __attribute__((address_space(3))) unsigned int* las_u32p;

__device__ __forceinline__ void load16_to_lds(const void* gptr, void* lptr) {
    // async global->LDS, 16 B per lane; LDS dst = wave-uniform base + lane*16
    __builtin_amdgcn_global_load_lds((gas_u32p)gptr, (las_u32p)lptr, 16, 0, 0);
}

__device__ __forceinline__ unsigned short f2bf(float f) {
    unsigned int u = __float_as_uint(f);
    u += 0x7FFFu + ((u >> 16) & 1u);   // RNE; finite inputs
    return (unsigned short)(u >> 16);
}

// --------------------------------------------------------------------------
// fp32 -> bf16 prepass, one launch, block-uniform segment selection.
// x: blocks 0..2047, W_fc: 2048..3071, W_proj: 3072..4095; 1024 float4/block.
// --------------------------------------------------------------------------
__global__ __launch_bounds__(256)
void cvt_all(const float4* __restrict__ x,  ushort4* __restrict__ xb,
             const float4* __restrict__ wf, ushort4* __restrict__ wfb,
             const float4* __restrict__ wp, ushort4* __restrict__ wpb)
{
    const int b = blockIdx.x;
    const float4* s; ushort4* d; int base;
    if (b < 2048)      { s = x;  d = xb;  base = b * 1024; }
    else if (b < 3072) { s = wf; d = wfb; base = (b - 2048) * 1024; }
    else               { s = wp; d = wpb; base = (b - 3072) * 1024; }
    const int i0 = base + threadIdx.x;
    #pragma unroll
    for (int j = 0; j < 4; j++) {
        float4 v = s[i0 + j * 256];
        ushort4 o;
        o.x = f2bf(v.x); o.y = f2bf(v.y); o.z = f2bf(v.z); o.w = f2bf(v.w);
        d[i0 + j * 256] = o;
    }
}

// --------------------------------------------------------------------------
// C[M,N] = A[M,K] . B[N,K]^T  (bf16-as-ushort in, fp32 accum), 512 threads.
// BM x BN block tile; 8 waves in NWM x NWN grid; wave tile (BM/NWM)x(BN/NWN).
// m97 staging: global_load_lds w=16, row-major [rows][64] LDS, 2 barriers.
// RELU2: relu(v)^2 epilogue. OUT_BF16: bf16 store else fp32.
// Requires M%BM==0, N%BN==0, K%64==0.
// --------------------------------------------------------------------------
template<int BM, int BN, int NWM, int NWN, bool RELU2, bool OUT_BF16>
__global__ __launch_bounds__(512, 2)
void gemm_bt(const unsigned short* __restrict__ A,
             const unsigned short* __restrict__ B,
             void* __restrict__ Cv, int M, int N, int K)
{
    constexpr int WR = BM / NWM;       // wave tile rows
    constexpr int WC = BN / NWN;       // wave tile cols
    constexpr int AI = WR / 16;        // acc tiles in M per wave
    constexpr int AJ = WC / 16;        // acc tiles in N per wave
    constexpr int CA = BM / 64;        // A staging chunks (8 KB each)
    constexpr int CB = BN / 64;        // B staging chunks

    __shared__ unsigned short sA[BM * BK];
    __shared__ unsigned short sB[BN * BK];

    const int tid  = threadIdx.x;      // 0..511
    const int lane = tid & 63;
    const int wave = tid >> 6;         // 0..7
    const int wmr  = (wave / NWN) * WR;
    const int wnc  = (wave % NWN) * WC;
    const int quad = lane >> 4;
    const int m16  = lane & 15;

    const long bm0 = (long)blockIdx.y * BM;
    const long bn0 = (long)blockIdx.x * BN;

    // staging: chunk c: row = c*64 + tid/8, slot = tid&7 (16 B);
    // LDS byte off = c*8192 + tid*16  (row*128 + slot*16) — wave-uniform+lane*16.
    const int srow = tid >> 3;                 // 0..63
    const int scol = (tid & 7) * 8;            // element offset

    const unsigned short* gA = A + (bm0 + srow) * (long)K + scol;
    const unsigned short* gB = B + (bn0 + srow) * (long)K + scol;
    char* lA = (char*)sA + tid * 16;
    char* lB = (char*)sB + tid * 16;

    f32x4 acc[AI][AJ];
    #pragma unroll
    for (int i = 0; i < AI; i++)
        #pragma unroll
        for (int j = 0; j < AJ; j++)
            acc[i][j] = (f32x4)0.0f;

    for (int k0 = 0; k0 < K; k0 += BK) {
        #pragma unroll
        for (int c = 0; c < CA; c++)
            load16_to_lds(gA + (long)c * 64 * K + k0, lA + c * 8192);
        #pragma unroll
        for (int c = 0; c < CB; c++)
            load16_to_lds(gB + (long)c * 64 * K + k0, lB + c * 8192);
        __syncthreads();

        #pragma unroll
        for (int h = 0; h < 2; h++) {          // two K=32 halves
            bf16x8 af[AI], bfr[AJ];
            #pragma unroll
            for (int i = 0; i < AI; i++)
                af[i]  = *(const bf16x8*)&sA[(wmr + i * 16 + m16) * BK + h * 32 + quad * 8];
            #pragma unroll
            for (int j = 0; j < AJ; j++)
                bfr[j] = *(const bf16x8*)&sB[(wnc + j * 16 + m16) * BK + h * 32 + quad * 8];

            #pragma unroll
            for (int i = 0; i < AI; i++)
                #pragma unroll
                for (int j = 0; j < AJ; j++)
                    acc[i][j] = __builtin_amdgcn_mfma_f32_16x16x32_bf16(
                        af[i], bfr[j], acc[i][j], 0, 0, 0);
        }
        __syncthreads();
    }

    // epilogue: C/D layout col=lane&15, row=quad*4+reg (m89/m91)
    #pragma unroll
    for (int i = 0; i < AI; i++) {
        #pragma unroll
        for (int j = 0; j < AJ; j++) {
            #pragma unroll
            for (int r = 0; r < 4; r++) {
                float v = acc[i][j][r];
                if (RELU2) v = (v > 0.0f) ? v * v : 0.0f;
                const long row = bm0 + wmr + i * 16 + quad * 4 + r;
                const long col = bn0 + wnc + j * 16 + m16;
                if (OUT_BF16)
                    ((unsigned short*)Cv)[row * (long)N + col] = f2bf(v);
                else
                    ((float*)Cv)[row * (long)N + col] = v;
            }
        }
    }
}

extern "C" void kernel_launch(void* const* d_in, const int* in_sizes, int n_in,
                              void* d_out, int out_size, void* d_ws, size_t ws_size,
                              hipStream_t stream) {
    (void)in_sizes; (void)n_in; (void)out_size; (void)ws_size;

    const int T = 8192, DIM = 1024, HID = 4096;

    const float* x     = (const float*)d_in[0];  // [T, DIM]
    const float* W_fc  = (const float*)d_in[1];  // [HID, DIM]
    const float* W_prj = (const float*)d_in[2];  // [DIM, HID]
    float* out = (float*)d_out;                  // [T, DIM]

    char* ws = (char*)d_ws;
    unsigned short* h   = (unsigned short*)ws;                  // 64 MiB [T,HID]
    unsigned short* xb  = (unsigned short*)(ws + (64l << 20));  // 16 MiB
    unsigned short* wfb = (unsigned short*)(ws + (80l << 20));  //  8 MiB
    unsigned short* wpb = (unsigned short*)(ws + (88l << 20));  //  8 MiB

    // prepass: all three fp32 -> bf16 in ONE launch
    cvt_all<<<4096, 256, 0, stream>>>(
        (const float4*)x,     (ushort4*)xb,
        (const float4*)W_fc,  (ushort4*)wfb,
        (const float4*)W_prj, (ushort4*)wpb);

    // GEMM1: h = relu(x . W_fc^T)^2  [8192,4096] bf16; 256x256 tile
    gemm_bt<256, 256, 2, 4, true, true>
        <<<dim3(HID / 256, T / 256), dim3(512), 0, stream>>>(
            xb, wfb, h, T, HID, DIM);

    // GEMM2: out = h . W_proj^T      [8192,1024] fp32; 256x128 tile
    gemm_bt<256, 128, 4, 2, false, false>
        <<<dim3(DIM / 128, T / 256), dim3(512), 0, stream>>>(
            h, wpb, out, T, DIM, HID);
}